// Round 7
// baseline (143.619 us; speedup 1.0000x reference)
//
#include <hip/hip_runtime.h>
#include <cstdint>

#define BB 2
#define NN 4096
#define MM 4096
#define KK 32
#define CC 64
#define R2C 0.0064f   // RADIUS^2

typedef _Float16 v8h __attribute__((ext_vector_type(8)));
typedef _Float16 v4h __attribute__((ext_vector_type(4)));
typedef float    v4f __attribute__((ext_vector_type(4)));

#define H1S 136    // H1 stride: 128 + 8 (272 B)
#define H2S 72     // H2 stride: 64 + 8 (144 B)

#define NBLK_HEAVY  1024   // 8 points each, dispatched FIRST
#define NBLK_COLMIN 512    // 16 m each, backfill the 5th slot + tail
#define NBLK_TOTAL  1536

// ---------------------------------------------------------------------------
// Dispatch A (prep, 568 blocks — fully parallel, ~5 µs):
//   blocks [  0,512): transpose feat (B,C,M) f32 -> featH (B,M,C) f16.
//   blocks [512,560): pack weights to f16 A-operand layouts.
//   blocks [560,568): pack knn -> knnP float4 (x,y,z,|k|^2), same fp32 op
//                     order as the original staging pass -> identical d2 bits.
// ---------------------------------------------------------------------------
__launch_bounds__(256)
__global__ void prep_kernel(const float* __restrict__ knn,
                            const float* __restrict__ feat,
                            const float* __restrict__ w1,
                            const float* __restrict__ w2,
                            const float* __restrict__ w3,
                            _Float16* __restrict__ featH,
                            _Float16* __restrict__ w1h,
                            _Float16* __restrict__ w2h,
                            _Float16* __restrict__ w3h,
                            float4* __restrict__ knnP) {
    __shared__ float tl[64][17];
    int t = threadIdx.x, blk = blockIdx.x;

    if (blk < 512) {
        // ---- feat transpose: 16c x 64m tile ----
        int b = blk >> 8;
        int tb = blk & 255;                 // 4 c-quarters x 64 m-tiles
        int c0 = (tb >> 6) * 16;
        int m0 = (tb & 63) * 64;
        const float* src = feat + (size_t)b * CC * MM;
        int mi = t & 63, cg = t >> 6;       // cg in 0..3
#pragma unroll
        for (int r = 0; r < 4; ++r) {
            int cl = cg * 4 + r;
            tl[mi][cl] = src[(size_t)(c0 + cl) * MM + m0 + mi];
        }
        __syncthreads();
        int mm2 = t >> 2, j4 = (t & 3) * 4;
        _Float16* dst = featH + ((size_t)b * MM + m0 + mm2) * CC + c0 + j4;
        v4h v;
#pragma unroll
        for (int j = 0; j < 4; ++j) v[j] = (_Float16)tl[mm2][j4 + j];
        *(v4h*)dst = v;
    } else if (blk < 560) {
        // ---- weight pack ----
        int tt = (blk - 512) * 256 + t;        // < 12288
        if (tt < 128 * 96) {
            int r = tt / 96, k = tt - r * 96;
            w1h[tt] = (_Float16)((k < 68) ? w1[r * 68 + k] : 0.0f);
        }
        if (tt < 64 * 128) w2h[tt] = (_Float16)w2[tt];
        if (tt < 64 * 64)  w3h[tt] = (_Float16)w3[tt];
    } else {
        // ---- knnP pack ----
        int i0 = (blk - 560) * 256 + t;        // 0..2047
#pragma unroll
        for (int j = 0; j < 4; ++j) {
            int i = i0 + 2048 * j;             // 0..8191
            int b = i >> 12, m = i & (MM - 1);
            const float* kp = knn + (size_t)b * 3 * MM;
            float x = kp[m], y = kp[MM + m], z = kp[2 * MM + m];
            float e = __fadd_rn(__fadd_rn(__fmul_rn(x, x), __fmul_rn(y, y)),
                                __fmul_rn(z, z));
            knnP[i] = make_float4(x, y, z, e);
        }
    }
}

// ---------------------------------------------------------------------------
// Dispatch B (fused, 1536 blocks; LDS ~29.7 KB -> 5 blocks/CU resident):
//   blocks [   0,1024): select8 + MLP — wave owns 2 points, scans all 4096
//     candidates from L2 (knnP 128 KB resident; zero select barriers).
//     Ballot compaction == reference top-k-of-masked-index. Wave-local meta
//     (own rows, register P) -> ONE barrier before the MLP. 4 MLP passes of
//     64 cols, 2 barriers/pass, layer-1 B-operands from featH at use site
//     (no cross-barrier register prefetch — round-5 spill trap).
//   blocks [1024,1536): colmin — 16 m each (proven staged code, Kp from
//     knnP: identical bits). Backfills the 5th CU slot + drain tail.
// Loss: plain stores to unique slots; loss_kernel reduces (stream order).
// ---------------------------------------------------------------------------
__launch_bounds__(256, 5)
__global__ void fused_kernel(const float* __restrict__ points,
                             const float4* __restrict__ knnP,
                             const _Float16* __restrict__ featH,
                             const _Float16* __restrict__ w1h, const float* __restrict__ b1,
                             const _Float16* __restrict__ w2h, const float* __restrict__ b2,
                             const _Float16* __restrict__ w3h, const float* __restrict__ b3,
                             float* __restrict__ lossbuf,
                             float* __restrict__ out) {
    __shared__ __align__(16) _Float16 SM[64 * H1S + 64 * H2S];  // 26624 B
    _Float16* H1 = SM;                       // colmin tile aliases [0,16384)
    _Float16* H2 = SM + 64 * H1S;
    __shared__ int    sidx_f[8][KK];         // 1024 B
    __shared__ v4h    meta[8][KK];           // 2048 B
    __shared__ float  ws4[4];

    int t = threadIdx.x;
    int w = t >> 6, lane = t & 63;
    int blk = blockIdx.x;

    if (blk >= NBLK_HEAVY) {
        // ================= colmin: 16 m per block =================
        int cb = blk - NBLK_HEAVY;
        float4* tile = (float4*)SM;
        int m0 = cb * 16;
        int b = cb >> 8;
        const float* pp = points + (size_t)b * 3 * NN;
        const float4* kq = knnP + (size_t)b * MM;
        float4 Kp[4];
#pragma unroll
        for (int p = 0; p < 4; ++p)
            Kp[p] = kq[(m0 & (MM - 1)) + 4 * w + p];
        float mn[4] = {1e30f, 1e30f, 1e30f, 1e30f};

        for (int ch = 0; ch < 4; ++ch) {
            const float* px = pp + ch * 1024;
#pragma unroll
            for (int j = 0; j < 4; ++j) {
                int i = t + 256 * j;
                float x = px[i], y = px[NN + i], z = px[2 * NN + i];
                float e = __fadd_rn(__fadd_rn(__fmul_rn(x, x), __fmul_rn(y, y)),
                                    __fmul_rn(z, z));
                tile[i] = make_float4(x, y, z, e);
            }
            __syncthreads();
#pragma unroll 2
            for (int i = 0; i < 16; ++i) {
                float4 p4 = tile[i * 64 + lane];
#pragma unroll
                for (int p = 0; p < 4; ++p) {
                    float cross = __builtin_fmaf(p4.z, Kp[p].z,
                                  __builtin_fmaf(p4.y, Kp[p].y,
                                                 __fmul_rn(p4.x, Kp[p].x)));
                    float d2 = __fsub_rn(__fadd_rn(p4.w, Kp[p].w),
                                         __fmul_rn(2.0f, cross));
                    mn[p] = fminf(mn[p], d2);
                }
            }
            __syncthreads();
        }

        float lsum = 0.0f;
#pragma unroll
        for (int p = 0; p < 4; ++p) {
            float mv = mn[p];
            for (int off = 32; off > 0; off >>= 1)
                mv = fminf(mv, __shfl_xor(mv, off));
            lsum += sqrtf(1e-6f + fmaxf(mv, 0.0f));
        }
        if (lane == 0) ws4[w] = lsum;
        __syncthreads();
        if (t == 0)
            lossbuf[NBLK_HEAVY + cb] = (ws4[0] + ws4[1] + ws4[2] + ws4[3])
                                       * (1.0f / (BB * MM));
    } else {
        // ================= select8 + MLP: 8 points per block ===============
        int pt0 = blk * 8;
        int b = pt0 >> 12;
        int n0 = pt0 & (NN - 1);
        const float* pp = points + (size_t)b * 3 * NN;
        const float4* kq = knnP + (size_t)b * MM;

        int quad = lane >> 4, lc = lane & 15;

        // ---- preload A-fragments + biases (latency hides under select) ----
        v8h a1[2][3], a2[4], a3[2];
#pragma unroll
        for (int rt = 0; rt < 2; ++rt)
#pragma unroll
            for (int ks = 0; ks < 3; ++ks)
                a1[rt][ks] = *(const v8h*)(w1h + (32 * w + 16 * rt + lc) * 96 + 32 * ks + 8 * quad);
#pragma unroll
        for (int ks = 0; ks < 4; ++ks)
            a2[ks] = *(const v8h*)(w2h + (16 * w + lc) * 128 + 32 * ks + 8 * quad);
#pragma unroll
        for (int ks = 0; ks < 2; ++ks)
            a3[ks] = *(const v8h*)(w3h + (16 * w + lc) * 64 + 32 * ks + 8 * quad);

        v4f bias1a = *(const v4f*)(b1 + 32 * w + 4 * quad);
        v4f bias1b = *(const v4f*)(b1 + 32 * w + 16 + 4 * quad);
        v4f bias2  = *(const v4f*)(b2 + 16 * w + 4 * quad);
        v4f bias3  = *(const v4f*)(b3 + 16 * w + 4 * quad);

        // ---- select: wave w owns points 2w, 2w+1; scan all 4096 from L2 ----
        float4 P[2];
#pragma unroll
        for (int p = 0; p < 2; ++p) {
            int nl = n0 + 2 * w + p;
            float x = pp[nl], y = pp[NN + nl], z = pp[2 * NN + nl];
            float e = __fadd_rn(__fadd_rn(__fmul_rn(x, x), __fmul_rn(y, y)),
                                __fmul_rn(z, z));
            P[p] = make_float4(x, y, z, e);
        }

        int cnt[2] = {0, 0};
        float mn[2] = {1e30f, 1e30f};
#pragma unroll 4
        for (int it = 0; it < 64; ++it) {
            int m = it * 64 + lane;
            float4 k4 = kq[m];
#pragma unroll
            for (int p = 0; p < 2; ++p) {
                float cross = __builtin_fmaf(P[p].z, k4.z,
                              __builtin_fmaf(P[p].y, k4.y,
                                             __fmul_rn(P[p].x, k4.x)));
                float d2 = __fsub_rn(__fadd_rn(P[p].w, k4.w),
                                     __fmul_rn(2.0f, cross));
                mn[p] = fminf(mn[p], d2);
                bool hit = d2 < R2C;
                unsigned long long mask = __ballot(hit);
                if (mask) {                      // wave-uniform skip
                    if (hit) {
                        int pos = cnt[p] + __builtin_amdgcn_mbcnt_hi(
                                     (unsigned)(mask >> 32),
                                     __builtin_amdgcn_mbcnt_lo((unsigned)mask, 0));
                        if (pos < KK) sidx_f[2 * w + p][pos] = m;
                    }
                    cnt[p] += __popcll(mask);
                }
            }
        }

        // ---- fill + row-min loss (wave-local, proven semantics) ----
        float lsum = 0.0f;
#pragma unroll
        for (int p = 0; p < 2; ++p) {
            int row = 2 * w + p;
            if (lane < KK) {
                int fillv = (cnt[p] > 0) ? sidx_f[row][0] : 0;
                int v = (lane < cnt[p]) ? sidx_f[row][lane] : fillv;
                sidx_f[row][lane] = v;
            }
            float mv = mn[p];
            for (int off = 32; off > 0; off >>= 1)
                mv = fminf(mv, __shfl_xor(mv, off));
            lsum += sqrtf(1e-6f + fmaxf(mv, 0.0f));
        }
        if (lane == 0) ws4[w] = lsum;

        // ---- wave-local meta: own 2 rows, register P; no barrier needed ----
        {
            int row = 2 * w + (lane >> 5), kk = lane & 31;
            int id = sidx_f[row][kk];            // same-wave LDS visibility
            float4 k4 = kq[id];
            float4 Pm = (lane >= 32) ? P[1] : P[0];
            float dx = k4.x - Pm.x, dy = k4.y - Pm.y, dz = k4.z - Pm.z;
            float dd = __fadd_rn(__fadd_rn(__fmul_rn(dx, dx), __fmul_rn(dy, dy)),
                                 __fmul_rn(dz, dz));
            v4h mv;
            mv[0] = (_Float16)dx; mv[1] = (_Float16)dy;
            mv[2] = (_Float16)dz; mv[3] = (_Float16)dd;
            meta[row][kk] = mv;
        }
        __syncthreads();                      // sidx_f + meta + ws4 ready
        if (t == 0)
            lossbuf[blk] = (ws4[0] + ws4[1] + ws4[2] + ws4[3])
                           * (1.0f / (BB * NN));

        // ---- 4 MLP passes of 64 cols; loads at point of use; 2 bar/pass ----
        for (int q = 0; q < 4; ++q) {
            // layer 1: H1(128 x 64) = W1 x X (B direct from featH + meta)
#pragma unroll
            for (int ct = 0; ct < 4; ++ct) {
                int colb = 16 * ct + lc;
                int row = 2 * q + (ct >> 1), kk = colb & 31;
                int id = sidx_f[row][kk];
                const _Float16* frow = featH + ((size_t)(b * MM + id)) * CC;
                v8h bx0 = *(const v8h*)(frow + 8 * quad);
                v8h bx1 = *(const v8h*)(frow + 32 + 8 * quad);
                v4h mr = meta[row][kk];
                v8h bx2 = {(_Float16)0.f, (_Float16)0.f, (_Float16)0.f, (_Float16)0.f,
                           (_Float16)0.f, (_Float16)0.f, (_Float16)0.f, (_Float16)0.f};
                if (quad == 0) {
                    bx2[0] = mr[0]; bx2[1] = mr[1];
                    bx2[2] = mr[2]; bx2[3] = mr[3];
                }
                v4f acc0 = bias1a, acc1 = bias1b;
                acc0 = __builtin_amdgcn_mfma_f32_16x16x32_f16(a1[0][0], bx0, acc0, 0, 0, 0);
                acc1 = __builtin_amdgcn_mfma_f32_16x16x32_f16(a1[1][0], bx0, acc1, 0, 0, 0);
                acc0 = __builtin_amdgcn_mfma_f32_16x16x32_f16(a1[0][1], bx1, acc0, 0, 0, 0);
                acc1 = __builtin_amdgcn_mfma_f32_16x16x32_f16(a1[1][1], bx1, acc1, 0, 0, 0);
                acc0 = __builtin_amdgcn_mfma_f32_16x16x32_f16(a1[0][2], bx2, acc0, 0, 0, 0);
                acc1 = __builtin_amdgcn_mfma_f32_16x16x32_f16(a1[1][2], bx2, acc1, 0, 0, 0);
                v4h h0, h1v;
#pragma unroll
                for (int r = 0; r < 4; ++r) {
                    h0[r]  = (_Float16)fmaxf(acc0[r], 0.0f);
                    h1v[r] = (_Float16)fmaxf(acc1[r], 0.0f);
                }
                *(v4h*)(H1 + colb * H1S + 32 * w + 4 * quad)      = h0;
                *(v4h*)(H1 + colb * H1S + 32 * w + 16 + 4 * quad) = h1v;
            }
            __syncthreads();

            // layer 2: H2(64 x 64) = W2 x H1
#pragma unroll 1
            for (int ct = 0; ct < 4; ++ct) {
                int colb = 16 * ct + lc;
                v4f acc = bias2;
#pragma unroll
                for (int ks = 0; ks < 4; ++ks) {
                    v8h bx = *(const v8h*)(H1 + colb * H1S + 32 * ks + 8 * quad);
                    acc = __builtin_amdgcn_mfma_f32_16x16x32_f16(a2[ks], bx, acc, 0, 0, 0);
                }
                v4h h;
#pragma unroll
                for (int r = 0; r < 4; ++r) h[r] = (_Float16)fmaxf(acc[r], 0.0f);
                *(v4h*)(H2 + colb * H2S + 16 * w + 4 * quad) = h;
            }
            __syncthreads();

            // layer 3 + ReLU + sum over k + store agg (no trailing barrier:
            // next-pass H1 writes ordered vs H1 reads by the bar after L1;
            // next-pass H2 writes ordered vs our H2 reads by its L2 bar)
#pragma unroll 1
            for (int p = 0; p < 2; ++p) {
                int cA = (2 * p) * 16 + lc, cB = (2 * p + 1) * 16 + lc;
                v4f accA = bias3, accB = bias3;
#pragma unroll
                for (int ks = 0; ks < 2; ++ks) {
                    v8h bA = *(const v8h*)(H2 + cA * H2S + 32 * ks + 8 * quad);
                    v8h bB = *(const v8h*)(H2 + cB * H2S + 32 * ks + 8 * quad);
                    accA = __builtin_amdgcn_mfma_f32_16x16x32_f16(a3[ks], bA, accA, 0, 0, 0);
                    accB = __builtin_amdgcn_mfma_f32_16x16x32_f16(a3[ks], bB, accB, 0, 0, 0);
                }
                v4f s;
#pragma unroll
                for (int r = 0; r < 4; ++r)
                    s[r] = fmaxf(accA[r], 0.0f) + fmaxf(accB[r], 0.0f);
#pragma unroll
                for (int off = 1; off < 16; off <<= 1) {
#pragma unroll
                    for (int r = 0; r < 4; ++r) s[r] += __shfl_xor(s[r], off);
                }
                if (lc == 0) {
                    int n = n0 + 2 * q + p;
                    int rowb = 16 * w + 4 * quad;
#pragma unroll
                    for (int r = 0; r < 4; ++r)
                        out[((size_t)(b * 64 + rowb + r)) * NN + n] = s[r];
                }
            }
        }
    }
}

// ---------------------------------------------------------------------------
// Dispatch C: 1-block loss reduction over 1536 partial slots.
// ---------------------------------------------------------------------------
__launch_bounds__(256)
__global__ void loss_kernel(const float* __restrict__ lossbuf,
                            float* __restrict__ out) {
    __shared__ float ws4[4];
    int t = threadIdx.x;
    float s = 0.0f;
#pragma unroll
    for (int q = 0; q < 6; ++q)             // 6*256 == 1536
        s += lossbuf[t + 256 * q];
    for (int off = 32; off > 0; off >>= 1) s += __shfl_xor(s, off);
    if ((t & 63) == 0) ws4[t >> 6] = s;
    __syncthreads();
    if (t == 0)
        out[(size_t)BB * 64 * NN] = ws4[0] + ws4[1] + ws4[2] + ws4[3];
}

// ---------------------------------------------------------------------------
extern "C" void kernel_launch(void* const* d_in, const int* in_sizes, int n_in,
                              void* d_out, int out_size, void* d_ws, size_t ws_size,
                              hipStream_t stream) {
    const float* points = (const float*)d_in[0];
    const float* knn    = (const float*)d_in[1];
    const float* feat   = (const float*)d_in[2];
    const float* w1 = (const float*)d_in[3];
    const float* b1 = (const float*)d_in[4];
    const float* w2 = (const float*)d_in[5];
    const float* b2 = (const float*)d_in[6];
    const float* w3 = (const float*)d_in[7];
    const float* b3 = (const float*)d_in[8];
    float* out = (float*)d_out;

    char* ws = (char*)d_ws;
    _Float16*  featH   = (_Float16*)ws;                  // 1048576 B
    _Float16*  w1h     = (_Float16*)(ws + 1048576);      // 24576 B
    _Float16*  w2h     = (_Float16*)(ws + 1073152);      // 16384 B
    _Float16*  w3h     = (_Float16*)(ws + 1089536);      // 8192 B
    float4*    knnP    = (float4*)(ws + 1097728);        // 131072 B
    float*     lossbuf = (float*)(ws + 1228800);         // 6144 B (1536 slots)

    prep_kernel<<<568, 256, 0, stream>>>(knn, feat, w1, w2, w3,
                                         featH, w1h, w2h, w3h, knnP);
    fused_kernel<<<NBLK_TOTAL, 256, 0, stream>>>(points, knnP, featH,
                                                 w1h, b1, w2h, b2, w3h, b3,
                                                 lossbuf, out);
    loss_kernel<<<1, 256, 0, stream>>>(lossbuf, out);
}

// Round 8
// 122.397 us; speedup vs baseline: 1.1734x; 1.1734x over previous
//
#include <hip/hip_runtime.h>
#include <cstdint>

#define BB 2
#define NN 4096
#define MM 4096
#define KK 32
#define CC 64
#define R2C 0.0064f   // RADIUS^2

typedef _Float16 v8h __attribute__((ext_vector_type(8)));
typedef _Float16 v4h __attribute__((ext_vector_type(4)));
typedef float    v4f __attribute__((ext_vector_type(4)));

#define H1S 136    // H1 stride: 128 + 8 (272 B)
#define H2S 72     // H2 stride: 64 + 8 (144 B)

#define NBLK_HEAVY  1024   // 8 points each, dispatched FIRST
#define NBLK_COLMIN 512    // 16 m each, backfill the drain tail
#define NBLK_TOTAL  1536

// ---------------------------------------------------------------------------
// Dispatch A (prep, 568 blocks — fully parallel, ~5 µs):
//   blocks [  0,512): transpose feat (B,C,M) f32 -> featH (B,M,C) f16.
//   blocks [512,560): pack weights to f16 A-operand layouts.
//   blocks [560,568): pack knn -> knnP float4 (x,y,z,|k|^2), same fp32 op
//                     order as the original staging pass -> identical d2 bits.
// ---------------------------------------------------------------------------
__launch_bounds__(256)
__global__ void prep_kernel(const float* __restrict__ knn,
                            const float* __restrict__ feat,
                            const float* __restrict__ w1,
                            const float* __restrict__ w2,
                            const float* __restrict__ w3,
                            _Float16* __restrict__ featH,
                            _Float16* __restrict__ w1h,
                            _Float16* __restrict__ w2h,
                            _Float16* __restrict__ w3h,
                            float4* __restrict__ knnP) {
    __shared__ float tl[64][17];
    int t = threadIdx.x, blk = blockIdx.x;

    if (blk < 512) {
        // ---- feat transpose: 16c x 64m tile ----
        int b = blk >> 8;
        int tb = blk & 255;                 // 4 c-quarters x 64 m-tiles
        int c0 = (tb >> 6) * 16;
        int m0 = (tb & 63) * 64;
        const float* src = feat + (size_t)b * CC * MM;
        int mi = t & 63, cg = t >> 6;       // cg in 0..3
#pragma unroll
        for (int r = 0; r < 4; ++r) {
            int cl = cg * 4 + r;
            tl[mi][cl] = src[(size_t)(c0 + cl) * MM + m0 + mi];
        }
        __syncthreads();
        int mm2 = t >> 2, j4 = (t & 3) * 4;
        _Float16* dst = featH + ((size_t)b * MM + m0 + mm2) * CC + c0 + j4;
        v4h v;
#pragma unroll
        for (int j = 0; j < 4; ++j) v[j] = (_Float16)tl[mm2][j4 + j];
        *(v4h*)dst = v;
    } else if (blk < 560) {
        // ---- weight pack ----
        int tt = (blk - 512) * 256 + t;        // < 12288
        if (tt < 128 * 96) {
            int r = tt / 96, k = tt - r * 96;
            w1h[tt] = (_Float16)((k < 68) ? w1[r * 68 + k] : 0.0f);
        }
        if (tt < 64 * 128) w2h[tt] = (_Float16)w2[tt];
        if (tt < 64 * 64)  w3h[tt] = (_Float16)w3[tt];
    } else {
        // ---- knnP pack ----
        int i0 = (blk - 560) * 256 + t;        // 0..2047
#pragma unroll
        for (int j = 0; j < 4; ++j) {
            int i = i0 + 2048 * j;             // 0..8191
            int b = i >> 12, m = i & (MM - 1);
            const float* kp = knn + (size_t)b * 3 * MM;
            float x = kp[m], y = kp[MM + m], z = kp[2 * MM + m];
            float e = __fadd_rn(__fadd_rn(__fmul_rn(x, x), __fmul_rn(y, y)),
                                __fmul_rn(z, z));
            knnP[i] = make_float4(x, y, z, e);
        }
    }
}

// ---------------------------------------------------------------------------
// Dispatch B (fused, 1536 blocks, __launch_bounds__(256,4) — the proven
// spill-free register budget; occupancy comes from the grid):
//   blocks [   0,1024): select8 + MLP — wave owns 2 points; scans all 4096
//     candidates from L2 via a DEPTH-2 SOFTWARE PIPELINE (ka/kb in flight,
//     guarded kc prefetch) so the ballot/compaction branch never blocks the
//     next loads. Ballot compaction == reference top-k-of-masked-index.
//     Wave-local meta (register P) -> one barrier before the MLP. 4 MLP
//     passes of 64 cols, 2 barriers/pass, layer-1 B-operands from featH at
//     use site (NO cross-barrier register prefetch — round-5 spill trap).
//   blocks [1024,1536): colmin — 16 m each (proven staged code, Kp from
//     knnP: identical bits). Backfills the drain tail.
// Loss: plain stores to unique slots; loss_kernel reduces (stream order).
// ---------------------------------------------------------------------------
__launch_bounds__(256, 4)
__global__ void fused_kernel(const float* __restrict__ points,
                             const float4* __restrict__ knnP,
                             const _Float16* __restrict__ featH,
                             const _Float16* __restrict__ w1h, const float* __restrict__ b1,
                             const _Float16* __restrict__ w2h, const float* __restrict__ b2,
                             const _Float16* __restrict__ w3h, const float* __restrict__ b3,
                             float* __restrict__ lossbuf,
                             float* __restrict__ out) {
    __shared__ __align__(16) _Float16 SM[64 * H1S + 64 * H2S];  // 26624 B
    _Float16* H1 = SM;                       // colmin tile aliases [0,16384)
    _Float16* H2 = SM + 64 * H1S;
    __shared__ int    sidx_f[8][KK];         // 1024 B
    __shared__ v4h    meta[8][KK];           // 2048 B
    __shared__ float  ws4[4];

    int t = threadIdx.x;
    int w = t >> 6, lane = t & 63;
    int blk = blockIdx.x;

    if (blk >= NBLK_HEAVY) {
        // ================= colmin: 16 m per block =================
        int cb = blk - NBLK_HEAVY;
        float4* tile = (float4*)SM;
        int m0 = cb * 16;
        int b = cb >> 8;
        const float* pp = points + (size_t)b * 3 * NN;
        const float4* kq = knnP + (size_t)b * MM;
        float4 Kp[4];
#pragma unroll
        for (int p = 0; p < 4; ++p)
            Kp[p] = kq[(m0 & (MM - 1)) + 4 * w + p];
        float mn[4] = {1e30f, 1e30f, 1e30f, 1e30f};

        for (int ch = 0; ch < 4; ++ch) {
            const float* px = pp + ch * 1024;
#pragma unroll
            for (int j = 0; j < 4; ++j) {
                int i = t + 256 * j;
                float x = px[i], y = px[NN + i], z = px[2 * NN + i];
                float e = __fadd_rn(__fadd_rn(__fmul_rn(x, x), __fmul_rn(y, y)),
                                    __fmul_rn(z, z));
                tile[i] = make_float4(x, y, z, e);
            }
            __syncthreads();
#pragma unroll 2
            for (int i = 0; i < 16; ++i) {
                float4 p4 = tile[i * 64 + lane];
#pragma unroll
                for (int p = 0; p < 4; ++p) {
                    float cross = __builtin_fmaf(p4.z, Kp[p].z,
                                  __builtin_fmaf(p4.y, Kp[p].y,
                                                 __fmul_rn(p4.x, Kp[p].x)));
                    float d2 = __fsub_rn(__fadd_rn(p4.w, Kp[p].w),
                                         __fmul_rn(2.0f, cross));
                    mn[p] = fminf(mn[p], d2);
                }
            }
            __syncthreads();
        }

        float lsum = 0.0f;
#pragma unroll
        for (int p = 0; p < 4; ++p) {
            float mv = mn[p];
            for (int off = 32; off > 0; off >>= 1)
                mv = fminf(mv, __shfl_xor(mv, off));
            lsum += sqrtf(1e-6f + fmaxf(mv, 0.0f));
        }
        if (lane == 0) ws4[w] = lsum;
        __syncthreads();
        if (t == 0)
            lossbuf[NBLK_HEAVY + cb] = (ws4[0] + ws4[1] + ws4[2] + ws4[3])
                                       * (1.0f / (BB * MM));
    } else {
        // ================= select8 + MLP: 8 points per block ===============
        int pt0 = blk * 8;
        int b = pt0 >> 12;
        int n0 = pt0 & (NN - 1);
        const float* pp = points + (size_t)b * 3 * NN;
        const float4* kq = knnP + (size_t)b * MM;

        int quad = lane >> 4, lc = lane & 15;

        // ---- preload A-fragments + biases (latency hides under select) ----
        v8h a1[2][3], a2[4], a3[2];
#pragma unroll
        for (int rt = 0; rt < 2; ++rt)
#pragma unroll
            for (int ks = 0; ks < 3; ++ks)
                a1[rt][ks] = *(const v8h*)(w1h + (32 * w + 16 * rt + lc) * 96 + 32 * ks + 8 * quad);
#pragma unroll
        for (int ks = 0; ks < 4; ++ks)
            a2[ks] = *(const v8h*)(w2h + (16 * w + lc) * 128 + 32 * ks + 8 * quad);
#pragma unroll
        for (int ks = 0; ks < 2; ++ks)
            a3[ks] = *(const v8h*)(w3h + (16 * w + lc) * 64 + 32 * ks + 8 * quad);

        v4f bias1a = *(const v4f*)(b1 + 32 * w + 4 * quad);
        v4f bias1b = *(const v4f*)(b1 + 32 * w + 16 + 4 * quad);
        v4f bias2  = *(const v4f*)(b2 + 16 * w + 4 * quad);
        v4f bias3  = *(const v4f*)(b3 + 16 * w + 4 * quad);

        // ---- select: wave w owns points 2w, 2w+1; depth-2 pipelined scan ---
        float4 P[2];
#pragma unroll
        for (int p = 0; p < 2; ++p) {
            int nl = n0 + 2 * w + p;
            float x = pp[nl], y = pp[NN + nl], z = pp[2 * NN + nl];
            float e = __fadd_rn(__fadd_rn(__fmul_rn(x, x), __fmul_rn(y, y)),
                                __fmul_rn(z, z));
            P[p] = make_float4(x, y, z, e);
        }

        int cnt[2] = {0, 0};
        float mn[2] = {1e30f, 1e30f};
        float4 ka = kq[lane];                 // it = 0 in flight
        float4 kb = kq[64 + lane];            // it = 1 in flight
#pragma unroll 2
        for (int it = 0; it < 64; ++it) {
            float4 kc = kb;
            if (it < 62) kc = kq[(it + 2) * 64 + lane];   // issue 2 ahead
            int m = it * 64 + lane;
#pragma unroll
            for (int p = 0; p < 2; ++p) {
                float cross = __builtin_fmaf(P[p].z, ka.z,
                              __builtin_fmaf(P[p].y, ka.y,
                                             __fmul_rn(P[p].x, ka.x)));
                float d2 = __fsub_rn(__fadd_rn(P[p].w, ka.w),
                                     __fmul_rn(2.0f, cross));
                mn[p] = fminf(mn[p], d2);
                bool hit = d2 < R2C;
                unsigned long long mask = __ballot(hit);
                if (mask) {                      // wave-uniform skip
                    if (hit) {
                        int pos = cnt[p] + __builtin_amdgcn_mbcnt_hi(
                                     (unsigned)(mask >> 32),
                                     __builtin_amdgcn_mbcnt_lo((unsigned)mask, 0));
                        if (pos < KK) sidx_f[2 * w + p][pos] = m;
                    }
                    cnt[p] += __popcll(mask);
                }
            }
            ka = kb; kb = kc;
        }

        // ---- fill + row-min loss (wave-local, proven semantics) ----
        float lsum = 0.0f;
#pragma unroll
        for (int p = 0; p < 2; ++p) {
            int row = 2 * w + p;
            if (lane < KK) {
                int fillv = (cnt[p] > 0) ? sidx_f[row][0] : 0;
                int v = (lane < cnt[p]) ? sidx_f[row][lane] : fillv;
                sidx_f[row][lane] = v;
            }
            float mv = mn[p];
            for (int off = 32; off > 0; off >>= 1)
                mv = fminf(mv, __shfl_xor(mv, off));
            lsum += sqrtf(1e-6f + fmaxf(mv, 0.0f));
        }
        if (lane == 0) ws4[w] = lsum;

        // ---- wave-local meta: own 2 rows, register P; no barrier needed ----
        {
            int row = 2 * w + (lane >> 5), kk = lane & 31;
            int id = sidx_f[row][kk];            // same-wave LDS visibility
            float4 k4 = kq[id];
            float4 Pm = (lane >= 32) ? P[1] : P[0];
            float dx = k4.x - Pm.x, dy = k4.y - Pm.y, dz = k4.z - Pm.z;
            float dd = __fadd_rn(__fadd_rn(__fmul_rn(dx, dx), __fmul_rn(dy, dy)),
                                 __fmul_rn(dz, dz));
            v4h mv;
            mv[0] = (_Float16)dx; mv[1] = (_Float16)dy;
            mv[2] = (_Float16)dz; mv[3] = (_Float16)dd;
            meta[row][kk] = mv;
        }
        __syncthreads();                      // sidx_f + meta + ws4 ready
        if (t == 0)
            lossbuf[blk] = (ws4[0] + ws4[1] + ws4[2] + ws4[3])
                           * (1.0f / (BB * NN));

        // ---- 4 MLP passes of 64 cols; loads at point of use; 2 bar/pass ----
        for (int q = 0; q < 4; ++q) {
            // layer 1: H1(128 x 64) = W1 x X (B direct from featH + meta)
#pragma unroll
            for (int ct = 0; ct < 4; ++ct) {
                int colb = 16 * ct + lc;
                int row = 2 * q + (ct >> 1), kk = colb & 31;
                int id = sidx_f[row][kk];
                const _Float16* frow = featH + ((size_t)(b * MM + id)) * CC;
                v8h bx0 = *(const v8h*)(frow + 8 * quad);
                v8h bx1 = *(const v8h*)(frow + 32 + 8 * quad);
                v4h mr = meta[row][kk];
                v8h bx2 = {(_Float16)0.f, (_Float16)0.f, (_Float16)0.f, (_Float16)0.f,
                           (_Float16)0.f, (_Float16)0.f, (_Float16)0.f, (_Float16)0.f};
                if (quad == 0) {
                    bx2[0] = mr[0]; bx2[1] = mr[1];
                    bx2[2] = mr[2]; bx2[3] = mr[3];
                }
                v4f acc0 = bias1a, acc1 = bias1b;
                acc0 = __builtin_amdgcn_mfma_f32_16x16x32_f16(a1[0][0], bx0, acc0, 0, 0, 0);
                acc1 = __builtin_amdgcn_mfma_f32_16x16x32_f16(a1[1][0], bx0, acc1, 0, 0, 0);
                acc0 = __builtin_amdgcn_mfma_f32_16x16x32_f16(a1[0][1], bx1, acc0, 0, 0, 0);
                acc1 = __builtin_amdgcn_mfma_f32_16x16x32_f16(a1[1][1], bx1, acc1, 0, 0, 0);
                acc0 = __builtin_amdgcn_mfma_f32_16x16x32_f16(a1[0][2], bx2, acc0, 0, 0, 0);
                acc1 = __builtin_amdgcn_mfma_f32_16x16x32_f16(a1[1][2], bx2, acc1, 0, 0, 0);
                v4h h0, h1v;
#pragma unroll
                for (int r = 0; r < 4; ++r) {
                    h0[r]  = (_Float16)fmaxf(acc0[r], 0.0f);
                    h1v[r] = (_Float16)fmaxf(acc1[r], 0.0f);
                }
                *(v4h*)(H1 + colb * H1S + 32 * w + 4 * quad)      = h0;
                *(v4h*)(H1 + colb * H1S + 32 * w + 16 + 4 * quad) = h1v;
            }
            __syncthreads();

            // layer 2: H2(64 x 64) = W2 x H1
#pragma unroll 1
            for (int ct = 0; ct < 4; ++ct) {
                int colb = 16 * ct + lc;
                v4f acc = bias2;
#pragma unroll
                for (int ks = 0; ks < 4; ++ks) {
                    v8h bx = *(const v8h*)(H1 + colb * H1S + 32 * ks + 8 * quad);
                    acc = __builtin_amdgcn_mfma_f32_16x16x32_f16(a2[ks], bx, acc, 0, 0, 0);
                }
                v4h h;
#pragma unroll
                for (int r = 0; r < 4; ++r) h[r] = (_Float16)fmaxf(acc[r], 0.0f);
                *(v4h*)(H2 + colb * H2S + 16 * w + 4 * quad) = h;
            }
            __syncthreads();

            // layer 3 + ReLU + sum over k + store agg (no trailing barrier:
            // next-pass H1 writes ordered vs H1 reads by the bar after L1;
            // next-pass H2 writes ordered vs our H2 reads by its L2 bar)
#pragma unroll 1
            for (int p = 0; p < 2; ++p) {
                int cA = (2 * p) * 16 + lc, cB = (2 * p + 1) * 16 + lc;
                v4f accA = bias3, accB = bias3;
#pragma unroll
                for (int ks = 0; ks < 2; ++ks) {
                    v8h bA = *(const v8h*)(H2 + cA * H2S + 32 * ks + 8 * quad);
                    v8h bB = *(const v8h*)(H2 + cB * H2S + 32 * ks + 8 * quad);
                    accA = __builtin_amdgcn_mfma_f32_16x16x32_f16(a3[ks], bA, accA, 0, 0, 0);
                    accB = __builtin_amdgcn_mfma_f32_16x16x32_f16(a3[ks], bB, accB, 0, 0, 0);
                }
                v4f s;
#pragma unroll
                for (int r = 0; r < 4; ++r)
                    s[r] = fmaxf(accA[r], 0.0f) + fmaxf(accB[r], 0.0f);
#pragma unroll
                for (int off = 1; off < 16; off <<= 1) {
#pragma unroll
                    for (int r = 0; r < 4; ++r) s[r] += __shfl_xor(s[r], off);
                }
                if (lc == 0) {
                    int n = n0 + 2 * q + p;
                    int rowb = 16 * w + 4 * quad;
#pragma unroll
                    for (int r = 0; r < 4; ++r)
                        out[((size_t)(b * 64 + rowb + r)) * NN + n] = s[r];
                }
            }
        }
    }
}

// ---------------------------------------------------------------------------
// Dispatch C: 1-block loss reduction over 1536 partial slots.
// ---------------------------------------------------------------------------
__launch_bounds__(256)
__global__ void loss_kernel(const float* __restrict__ lossbuf,
                            float* __restrict__ out) {
    __shared__ float ws4[4];
    int t = threadIdx.x;
    float s = 0.0f;
#pragma unroll
    for (int q = 0; q < 6; ++q)             // 6*256 == 1536
        s += lossbuf[t + 256 * q];
    for (int off = 32; off > 0; off >>= 1) s += __shfl_xor(s, off);
    if ((t & 63) == 0) ws4[t >> 6] = s;
    __syncthreads();
    if (t == 0)
        out[(size_t)BB * 64 * NN] = ws4[0] + ws4[1] + ws4[2] + ws4[3];
}

// ---------------------------------------------------------------------------
extern "C" void kernel_launch(void* const* d_in, const int* in_sizes, int n_in,
                              void* d_out, int out_size, void* d_ws, size_t ws_size,
                              hipStream_t stream) {
    const float* points = (const float*)d_in[0];
    const float* knn    = (const float*)d_in[1];
    const float* feat   = (const float*)d_in[2];
    const float* w1 = (const float*)d_in[3];
    const float* b1 = (const float*)d_in[4];
    const float* w2 = (const float*)d_in[5];
    const float* b2 = (const float*)d_in[6];
    const float* w3 = (const float*)d_in[7];
    const float* b3 = (const float*)d_in[8];
    float* out = (float*)d_out;

    char* ws = (char*)d_ws;
    _Float16*  featH   = (_Float16*)ws;                  // 1048576 B
    _Float16*  w1h     = (_Float16*)(ws + 1048576);      // 24576 B
    _Float16*  w2h     = (_Float16*)(ws + 1073152);      // 16384 B
    _Float16*  w3h     = (_Float16*)(ws + 1089536);      // 8192 B
    float4*    knnP    = (float4*)(ws + 1097728);        // 131072 B
    float*     lossbuf = (float*)(ws + 1228800);         // 6144 B (1536 slots)

    prep_kernel<<<568, 256, 0, stream>>>(knn, feat, w1, w2, w3,
                                         featH, w1h, w2h, w3h, knnP);
    fused_kernel<<<NBLK_TOTAL, 256, 0, stream>>>(points, knnP, featH,
                                                 w1h, b1, w2h, b2, w3h, b3,
                                                 lossbuf, out);
    loss_kernel<<<1, 256, 0, stream>>>(lossbuf, out);
}